// Round 4
// baseline (126.026 us; speedup 1.0000x reference)
//
#include <hip/hip_runtime.h>
#include <hip/hip_bf16.h>
#include <math.h>

// ---- problem constants ----
#define B_ROWS 512
#define D_K    512
#define C_CLS  100000

#define S_SCALE 64.0f
#define COS_M 0.8775825618903728f
#define SIN_M 0.479425538604203f
#define TH_C  (-0.8775825618903728f)    // cos(pi - m)
#define MM_C  0.2397127693021015f       // sin(pi - m) * m

#define LOG2E_S 92.33248261689366f      // 64 * log2(e)
#define M0      92.4f                   // fixed softmax bound: |cos|<=1 -> |L|<=92.33
#define LN2F    0.6931471805599453f

// ---- GEMM tile config ----
#define BM 256                          // rows per block (2 rowblocks)
#define BN 64                           // classes per chunk
#define NCHUNK 1563                     // ceil(100000/64) (last chunk padded w/ rn=0)
#define CPS 13                          // chunks per strip
#define NSTRIP 121                      // ceil(1563/13)

typedef __attribute__((ext_vector_type(8))) short short8;
typedef __attribute__((ext_vector_type(4))) float f32x4;

__device__ inline unsigned short f2bf(float f) {
    unsigned int u = __float_as_uint(f);
    u += 0x7fffu + ((u >> 16) & 1u);
    return (unsigned short)(u >> 16);
}
__device__ inline float fexp2(float x) {
#if __has_builtin(__builtin_amdgcn_exp2f)
    return __builtin_amdgcn_exp2f(x);
#else
    return exp2f(x);
#endif
}
__device__ inline void gload16(const void* g, void* lds) {
    __builtin_amdgcn_global_load_lds(
        (const __attribute__((address_space(1))) unsigned int*)g,
        (__attribute__((address_space(3))) unsigned int*)lds, 16, 0, 0);
}
#define VMCNT0() asm volatile("s_waitcnt vmcnt(0)" ::: "memory")

// ---------------- kernel 0: normalize x rows -> bf16 (+ 1/|x|) ----------------
__global__ __launch_bounds__(256) void xnorm_kernel(const float* __restrict__ x,
                                                    unsigned short* __restrict__ xnb,
                                                    float* __restrict__ xrn) {
    const int row = blockIdx.x;
    const int t = threadIdx.x;
    float a = x[row * D_K + t];
    float b = x[row * D_K + t + 256];
    float s = a * a + b * b;
    s += __shfl_xor(s, 1);  s += __shfl_xor(s, 2);  s += __shfl_xor(s, 4);
    s += __shfl_xor(s, 8);  s += __shfl_xor(s, 16); s += __shfl_xor(s, 32);
    __shared__ float sS[4];
    __shared__ float rn_sh;
    if ((t & 63) == 0) sS[t >> 6] = s;
    __syncthreads();
    if (t == 0) {
        float rn = 1.0f / sqrtf(sS[0] + sS[1] + sS[2] + sS[3]);
        rn_sh = rn;
        xrn[row] = rn;
    }
    __syncthreads();
    const float rn = rn_sh;
    xnb[row * D_K + t]       = f2bf(a * rn);
    xnb[row * D_K + t + 256] = f2bf(b * rn);
}

// ---------------- kernel 1: fully-fused strip GEMM ----------------
// Reads raw fp32 W, normalizes per chunk in-block, bf16 MFMA, fixed-M0 sumexp.
// 512 threads (8 waves), A[256][512] bf16 in registers, B dbuf 2x8KB in LDS.
__global__ __launch_bounds__(512, 2) void gemm_fused_kernel(
        const unsigned short* __restrict__ xnb,   // [512][512] bf16 normalized
        const float* __restrict__ w,              // [100000][512] fp32 raw
        float* __restrict__ partials) {           // [NSTRIP][512]
    const int t    = threadIdx.x;
    const int lane = t & 63;
    const int wid  = t >> 6;

    // XCD-pair swizzle: both rowblocks of a strip land on the same XCD (j%8).
    const int j    = blockIdx.x;
    const int xcd  = j & 7;
    const int slot = j >> 3;
    const int s    = xcd + 8 * (slot >> 1);
    const int rb   = slot & 1;
    if (s >= NSTRIP) return;
    const int R0    = rb * BM;
    const int cbase = s * (CPS * BN);
    const int rem   = NCHUNK - s * CPS;
    const int nch   = rem < CPS ? rem : CPS;

    __shared__ char  smem[32 * 1024];   // A-bounce (32KB) then B dbuf (2x8KB)
    __shared__ float rnorm_sh[64];

    const int l8    = lane >> 3;
    const int cbs   = ((lane & 7) ^ l8) << 4;   // pre-swizzled global source byte-col
    const int cl    = lane & 15;
    const int khalf = (lane >> 4) << 4;
    const int xorv  = (lane & 7) << 4;

    // ---- A prologue: 256 rows x 512 k -> registers via LDS bounce ----
    short8 afr[2][16];
    const char* gA = (const char*)xnb;
#pragma unroll
    for (int ks = 0; ks < 8; ++ks) {
#pragma unroll
        for (int i = 0; i < 4; ++i) {
            const int row = i * 64 + wid * 8 + l8;
            gload16(gA + (size_t)(R0 + row) * 1024 + ks * 128 + cbs,
                    smem + (i * 8 + wid) * 1024);
        }
        VMCNT0();
        __syncthreads();
#pragma unroll
        for (int m = 0; m < 2; ++m)
#pragma unroll
            for (int kk = 0; kk < 2; ++kk) {
                const int r = wid * 32 + m * 16 + cl;
                afr[m][ks * 2 + kk] =
                    *(const short8*)(smem + r * 128 + ((kk * 64 + khalf) ^ xorv));
            }
        __syncthreads();
    }

    // B staging identity (per thread, chunk-invariant parts)
    const int brow = t >> 3;            // 0..63: class row within chunk
    const int bg   = t & 7;             // phys 16B granule owned (write LINEAR t*16)
    const int srcg = bg ^ (brow & 7);   // swizzled source granule

    float sums[8] = {0.f, 0.f, 0.f, 0.f, 0.f, 0.f, 0.f, 0.f};

    for (int ci = 0; ci < nch; ++ci) {
        const int C0 = cbase + ci * BN;

        // ---- norm phase: 8-lane groups, one row each; lane sums 64 elems ----
        {
            const int g  = lane >> 3;
            const int il = lane & 7;
            const int r  = wid * 8 + g;
            const int c  = C0 + r;
            const int cc = c < C_CLS ? c : C_CLS - 1;
            const float* nr = w + (size_t)cc * D_K + il * 64;
            float ss = 0.f;
#pragma unroll
            for (int q = 0; q < 16; ++q) {
                float4 v = *(const float4*)(nr + q * 4);
                ss += v.x * v.x + v.y * v.y + v.z * v.z + v.w * v.w;
            }
            ss += __shfl_xor(ss, 1);
            ss += __shfl_xor(ss, 2);
            ss += __shfl_xor(ss, 4);
            if (il == 0) rnorm_sh[r] = (c < C_CLS) ? (1.0f / sqrtf(ss)) : 0.0f;
        }
        __syncthreads();

        const int bc  = C0 + brow;
        const int bcc = bc < C_CLS ? bc : C_CLS - 1;
        const float* bsrc = w + (size_t)bcc * D_K + srcg * 8;
        const float rn = rnorm_sh[brow];   // 0 for pad rows

        f32x4 acc[2][4];
#pragma unroll
        for (int m = 0; m < 2; ++m)
#pragma unroll
            for (int n = 0; n < 4; ++n) acc[m][n] = (f32x4){0.f, 0.f, 0.f, 0.f};

        // stage slice 0 into buf0
        {
            float4 pa = *(const float4*)(bsrc);
            float4 pb = *(const float4*)(bsrc + 4);
            short8 h;
            h[0] = (short)f2bf(pa.x * rn); h[1] = (short)f2bf(pa.y * rn);
            h[2] = (short)f2bf(pa.z * rn); h[3] = (short)f2bf(pa.w * rn);
            h[4] = (short)f2bf(pb.x * rn); h[5] = (short)f2bf(pb.y * rn);
            h[6] = (short)f2bf(pb.z * rn); h[7] = (short)f2bf(pb.w * rn);
            *(short8*)(smem + t * 16) = h;
        }
        __syncthreads();

#pragma unroll
        for (int k = 0; k < 8; ++k) {
            // issue next-slice loads before MFMA (latency hides under compute)
            float4 qa, qb;
            if (k < 7) {
                qa = *(const float4*)(bsrc + (k + 1) * 64);
                qb = *(const float4*)(bsrc + (k + 1) * 64 + 4);
            }
            // compute from buf[k&1]
            const char* sB = smem + (k & 1) * 8192;
#pragma unroll
            for (int kk = 0; kk < 2; ++kk) {
                const int coff = (kk * 64 + khalf) ^ xorv;
                short8 bfr[4];
#pragma unroll
                for (int n = 0; n < 4; ++n)
                    bfr[n] = *(const short8*)(sB + (n * 16 + cl) * 128 + coff);
#pragma unroll
                for (int m = 0; m < 2; ++m)
#pragma unroll
                    for (int n = 0; n < 4; ++n)
                        acc[m][n] = __builtin_amdgcn_mfma_f32_16x16x32_bf16(
                            afr[m][k * 2 + kk], bfr[n], acc[m][n], 0, 0, 0);
            }
            if (k == 7) {
                // fixed-M0 accumulation: sum += 2^(S*log2e*cos - M0)
#pragma unroll
                for (int m = 0; m < 2; ++m)
#pragma unroll
                    for (int jj = 0; jj < 4; ++jj)
#pragma unroll
                        for (int n = 0; n < 4; ++n)
                            sums[m * 4 + jj] +=
                                fexp2(fmaf(acc[m][n][jj], LOG2E_S, -M0));
            } else {
                // convert + swizzled write into buf[(k+1)&1]
                short8 h;
                h[0] = (short)f2bf(qa.x * rn); h[1] = (short)f2bf(qa.y * rn);
                h[2] = (short)f2bf(qa.z * rn); h[3] = (short)f2bf(qa.w * rn);
                h[4] = (short)f2bf(qb.x * rn); h[5] = (short)f2bf(qb.y * rn);
                h[6] = (short)f2bf(qb.z * rn); h[7] = (short)f2bf(qb.w * rn);
                *(short8*)(smem + ((k + 1) & 1) * 8192 + t * 16) = h;
            }
            __syncthreads();
        }
    }

    // ---- strip epilogue: reduce tracked rows across their 16 col-lanes ----
#pragma unroll
    for (int m = 0; m < 2; ++m)
#pragma unroll
        for (int jj = 0; jj < 4; ++jj) {
            float v = sums[m * 4 + jj];
            v += __shfl_xor(v, 1);
            v += __shfl_xor(v, 2);
            v += __shfl_xor(v, 4);
            v += __shfl_xor(v, 8);
            if ((lane & 15) == 0) {
                const int r = R0 + wid * 32 + m * 16 + (lane >> 4) * 4 + jj;
                partials[s * B_ROWS + r] = v;
            }
        }
}

// ---------------- kernel 2: target-class cosine (fp32 exact) ----------------
__global__ __launch_bounds__(256) void tdot_kernel(const float* __restrict__ x,
                                                   const float* __restrict__ w,
                                                   const int* __restrict__ tgt,
                                                   const float* __restrict__ xrn,
                                                   float* __restrict__ tdot) {
    const int wid = threadIdx.x >> 6;
    const int lane = threadIdx.x & 63;
    const int b = blockIdx.x * 4 + wid;
    const int tg = tgt[b];
    const float* xr = x + (size_t)b * D_K + lane * 8;
    const float* wr = w + (size_t)tg * D_K + lane * 8;
    float4 xa = *(const float4*)xr;
    float4 xb = *(const float4*)(xr + 4);
    float4 wa = *(const float4*)wr;
    float4 wb = *(const float4*)(wr + 4);
    float xw = xa.x * wa.x + xa.y * wa.y + xa.z * wa.z + xa.w * wa.w
             + xb.x * wb.x + xb.y * wb.y + xb.z * wb.z + xb.w * wb.w;
    float ww = wa.x * wa.x + wa.y * wa.y + wa.z * wa.z + wa.w * wa.w
             + wb.x * wb.x + wb.y * wb.y + wb.z * wb.z + wb.w * wb.w;
#pragma unroll
    for (int m = 1; m < 64; m <<= 1) {
        xw += __shfl_xor(xw, m);
        ww += __shfl_xor(ww, m);
    }
    if (lane == 0) tdot[b] = xw * xrn[b] / sqrtf(ww);
}

// ---------------- kernel 3: per-row loss (margin fixup) + mean ----------------
__global__ __launch_bounds__(512) void final_kernel(const float* __restrict__ partials,
                                                    const float* __restrict__ tdot,
                                                    float* __restrict__ out) {
    const int b = threadIdx.x;   // 512 threads = 8 waves
    float s2 = 0.f;
    for (int s = 0; s < NSTRIP; ++s) s2 += partials[s * B_ROWS + b];
    const float cst = tdot[b];
    float c2 = 1.0f - cst * cst;
    c2 = fminf(fmaxf(c2, 0.0f), 1.0f);
    const float sine = sqrtf(c2);
    float phi = cst * COS_M - sine * SIN_M;
    phi = (cst > TH_C) ? phi : (cst - MM_C);
    const float Lt = cst * LOG2E_S;
    const float Lp = phi * LOG2E_S;
    // swap plain-target term for margin term in the denominator
    s2 = s2 - fexp2(Lt - M0) + fexp2(Lp - M0);
    float loss = LN2F * (M0 + log2f(s2) - Lp);
    loss += __shfl_xor(loss, 1);  loss += __shfl_xor(loss, 2);
    loss += __shfl_xor(loss, 4);  loss += __shfl_xor(loss, 8);
    loss += __shfl_xor(loss, 16); loss += __shfl_xor(loss, 32);
    __shared__ float sW[8];
    if ((b & 63) == 0) sW[b >> 6] = loss;
    __syncthreads();
    if (b == 0) {
        float tot = 0.f;
#pragma unroll
        for (int wv = 0; wv < 8; ++wv) tot += sW[wv];
        out[0] = tot * (1.0f / (float)B_ROWS);
    }
}

extern "C" void kernel_launch(void* const* d_in, const int* in_sizes, int n_in,
                              void* d_out, int out_size, void* d_ws, size_t ws_size,
                              hipStream_t stream) {
    const float* x = (const float*)d_in[0];
    const float* w = (const float*)d_in[1];
    const int* tgt = (const int*)d_in[2];
    float* out = (float*)d_out;

    char* ws = (char*)d_ws;
    size_t off = 0;
    unsigned short* xnb = (unsigned short*)(ws + off);
    off += (size_t)B_ROWS * D_K * 2;                   // 512 KB
    off = (off + 255) & ~(size_t)255;
    float* xrn = (float*)(ws + off);
    off += B_ROWS * 4;
    off = (off + 255) & ~(size_t)255;
    float* partials = (float*)(ws + off);
    off += (size_t)NSTRIP * B_ROWS * 4;                // 248 KB
    off = (off + 255) & ~(size_t)255;
    float* tdot = (float*)(ws + off);
    off += B_ROWS * 4;

    xnorm_kernel<<<B_ROWS, 256, 0, stream>>>(x, xnb, xrn);
    gemm_fused_kernel<<<256, 512, 0, stream>>>(xnb, w, partials);
    tdot_kernel<<<B_ROWS / 4, 256, 0, stream>>>(x, w, tgt, xrn, tdot);
    final_kernel<<<1, 512, 0, stream>>>(partials, tdot, out);
}